// Round 5
// baseline (331.385 us; speedup 1.0000x reference)
//
#include <hip/hip_runtime.h>
#include <hip/hip_bf16.h>
#include <math.h>

#define NN 8192
#define HP 8194   // per-type rows incl 1 zero guard row each end
#define HD 256
#define DOUT 64

typedef __bf16 bf16_t;
typedef __bf16 bf16x8 __attribute__((ext_vector_type(8)));
typedef float f32x4 __attribute__((ext_vector_type(4)));

// ---------------- workspace layout (bytes) ----------------
#define H0_OFF 0ull
#define H1_OFF 16781312ull
#define PW_OFF 33562624ull          // 335872 granules * 16B = 5,373,952
#define TW_OFF 38936576ull
#define PS_OFF 38936832ull          // [256][256] f32 = 256KB
#define PM_OFF 39198976ull          // [256][256] f32 = 256KB (end 39461120, proven safe R3)
// pw granule indices
#define PWG_L1 0
#define PWG_SH(l) (8192 + (l)*32768)
#define PWG_TY(l) (73728 + (l)*131072)

__device__ __forceinline__ void glds16(const void* g, void* l) {
    __builtin_amdgcn_global_load_lds(
        (const __attribute__((address_space(1))) void*)g,
        (__attribute__((address_space(3))) void*)l, 16, 0, 0);
}

__device__ __forceinline__ float frelu(float v) { return v > 0.f ? v : 0.f; }

// =========================================================
// pack: fully-coalesced reads via per-block LDS transpose.
// Image granule layouts (match layer/lin1 glds exactly):
//  L1:     g = kt*1024 + ct*256 + j2*64 + lq*16 + lrow
//  SH/TY:  g = img + kt*4096 + ct*1024 + s*256 + j2*64 + lq*16 + lrow
//  granule elems e: B[k = kt*32 + lq*8 + e][n = ct*64 + j2*16 + lrow]
//  (conv: k within [0,256) per tap, s = tap+1)
// =========================================================
__global__ __launch_bounds__(256) void pack_kernel(
    const float* __restrict__ lin1_w, const float* __restrict__ lin_w,
    const float* __restrict__ rel_lin_w, const float* __restrict__ conv_w,
    const float* __restrict__ rel_conv_w, const float* __restrict__ trans_arch,
    const float* __restrict__ agg_arch, bf16_t* __restrict__ pw,
    float* __restrict__ tws, bf16_t* __restrict__ h0, bf16_t* __restrict__ h1) {
    __shared__ float lt[32 * 257];    // 32.9KB (lin path); conv path uses 64*100
    const int tid = threadIdx.x, bx = blockIdx.x;
    if (bx < 88) {
        // lin-family: block = (matrix m, kt). 32 k-rows x 256 n staged.
        int m = bx >> 3, kt = bx & 7;
        const float* src; size_t img; bool l1 = (m == 0);
        if (m == 0) { src = lin1_w; img = 0; }
        else if (m <= 2) { int l = m - 1; src = lin_w + (size_t)l * 65536; img = PWG_SH(l); }
        else { int u = m - 3; int l = u >> 2, tt = u & 3;
            src = rel_lin_w + (size_t)(l * 4 + tt) * 65536;
            img = PWG_TY(l) + (size_t)tt * 32768; }
        const float4* s4 = (const float4*)(src + (size_t)kt * 32 * 256);
#pragma unroll
        for (int i = 0; i < 8; ++i) {
            int idx = tid + 256 * i;
            float4 v = s4[idx];
            int k = idx >> 6, n = (idx * 4) & 255;
            float* p = &lt[k * 257 + n];
            p[0] = v.x; p[1] = v.y; p[2] = v.z; p[3] = v.w;
        }
        __syncthreads();
        int j2 = tid >> 6, lq = (tid >> 4) & 3, lrow = tid & 15;
#pragma unroll
        for (int ct = 0; ct < 4; ++ct) {
            int n = ct * 64 + j2 * 16 + lrow;
            bf16x8 wv;
#pragma unroll
            for (int e = 0; e < 8; ++e) wv[e] = (bf16_t)lt[(lq * 8 + e) * 257 + n];
            size_t g = l1 ? (img + (size_t)kt * 1024 + ct * 256 + tid)
                          : (img + (size_t)kt * 4096 + ct * 1024 + tid);
            *(bf16x8*)(pw + g * 8) = wv;
        }
    } else if (bx < 408) {
        // conv-family: block = (inst, kt, ct). 64 n-rows x 96 floats staged.
        int idx = bx - 88;
        int inst = idx >> 5, r = idx & 31, kt = r >> 2, ct = r & 3;
        const float* src; size_t img;
        if (inst < 2) { src = conv_w + (size_t)inst * 196608; img = PWG_SH(inst); }
        else { int u = inst - 2; int l = u >> 2, tt = u & 3;
            src = rel_conv_w + (size_t)(l * 4 + tt) * 196608;
            img = PWG_TY(l) + (size_t)tt * 32768; }
        {
            int rl = tid >> 2, q0 = tid & 3;
            int n = ct * 64 + rl;
            const float4* rb = (const float4*)(src) + (size_t)n * 192 + kt * 24;
#pragma unroll
            for (int i = 0; i < 6; ++i) {
                float4 v = rb[q0 + 4 * i];
                float* p = &lt[rl * 100 + (q0 + 4 * i) * 4];
                p[0] = v.x; p[1] = v.y; p[2] = v.z; p[3] = v.w;
            }
        }
        __syncthreads();
        int j2 = tid >> 6, lq = (tid >> 4) & 3, lrow = tid & 15;
        int nl = j2 * 16 + lrow;
#pragma unroll
        for (int s = 1; s <= 3; ++s) {
            bf16x8 wv;
#pragma unroll
            for (int e = 0; e < 8; ++e) wv[e] = (bf16_t)lt[nl * 100 + (lq * 8 + e) * 3 + (s - 1)];
            size_t g = img + (size_t)kt * 4096 + ct * 1024 + s * 256 + tid;
            *(bf16x8*)(pw + g * 8) = wv;
        }
    } else if (bx == 408) {
        // zero guard rows of both h buffers
        for (int i = tid; i < 4096; i += 256) {
            int row_id = i >> 8, col = i & 255;
            int buf = row_id >> 3, t_ = (row_id >> 1) & 3, side = row_id & 1;
            bf16_t* hb = buf ? h1 : h0;
            hb[((size_t)t_ * HP + (side ? (HP - 1) : 0)) * HD + col] = (bf16_t)0.f;
        }
    } else {
        if (tid == 0) {
            for (int l = 0; l < 2; ++l) {
                float m = trans_arch[l * 5];
                for (int i = 1; i < 5; ++i) m = fmaxf(m, trans_arch[l * 5 + i]);
                float e[5], s = 0.f;
                for (int i = 0; i < 5; ++i) { e[i] = __expf(trans_arch[l * 5 + i] - m); s += e[i]; }
                for (int i = 0; i < 5; ++i) tws[l * 5 + i] = e[i] / s;
            }
            float m = fmaxf(fmaxf(agg_arch[0], agg_arch[1]), agg_arch[2]);
            float e0 = __expf(agg_arch[0] - m), e1 = __expf(agg_arch[1] - m), e2 = __expf(agg_arch[2] - m);
            float s = e0 + e1 + e2;
            tws[10] = e0 / s; tws[11] = e1 / s; tws[12] = e2 / s;
        }
    }
}

__device__ __forceinline__ void load_af(bf16x8 af[4], const bf16_t* lA,
                                        int sh, int wm, int lrow, int lq) {
#pragma unroll
    for (int i = 0; i < 4; ++i)
        af[i] = *(const bf16x8*)&lA[(sh + wm + i * 16 + lrow) * 40 + lq * 8];
}

__device__ __forceinline__ void do_mat(const bf16x8 af[4], const bf16_t* Bb,
                                       int grpbase, int lane, f32x4 acc[4][2]) {
#pragma unroll
    for (int j = 0; j < 2; ++j) {
        bf16x8 bfr = *(const bf16x8*)&Bb[(grpbase + j) * 512 + lane * 8];
#pragma unroll
        for (int i = 0; i < 4; ++i)
            acc[i][j] = __builtin_amdgcn_mfma_f32_16x16x32_bf16(af[i], bfr, acc[i][j], 0, 0, 0);
    }
}

// =========================================================
// lin1 (fused fp32->bf16): h0 = x @ lin1_w + b. 64x256 tile, x read once.
// =========================================================
__global__ __launch_bounds__(256, 2) void lin1_kernel(
    const float* __restrict__ x, bf16_t* __restrict__ h0,
    const bf16_t* __restrict__ pwL1, const float* __restrict__ b) {
    __shared__ __align__(16) bf16_t lA[64 * 40];
    __shared__ __align__(16) bf16_t lB[8192];
    const int tid = threadIdx.x, lane = tid & 63, wid = tid >> 6;
    const int bx = blockIdx.x;
    const int t = bx >> 7, mt = bx & 127;
    const int m0 = mt * 64;
    const int lrow = lane & 15, lq = lane >> 4;
    const int r0 = tid >> 2, kq0 = tid & 3;
    const float* xT = x + (size_t)t * NN * HD + (size_t)(m0 + r0) * HD + kq0 * 8;

    f32x4 acc[4][4];
#pragma unroll
    for (int i = 0; i < 4; ++i)
#pragma unroll
        for (int j = 0; j < 4; ++j) acc[i][j] = (f32x4){0.f, 0.f, 0.f, 0.f};

    float4 px0, px1;
    { const float4* p = (const float4*)xT; px0 = p[0]; px1 = p[1]; }

    for (int kt = 0; kt < 8; ++kt) {
        __syncthreads();   // previous MFMA phase done with lA/lB
        bf16x8 wv;
        wv[0]=(bf16_t)px0.x; wv[1]=(bf16_t)px0.y; wv[2]=(bf16_t)px0.z; wv[3]=(bf16_t)px0.w;
        wv[4]=(bf16_t)px1.x; wv[5]=(bf16_t)px1.y; wv[6]=(bf16_t)px1.z; wv[7]=(bf16_t)px1.w;
        *(bf16x8*)&lA[r0 * 40 + kq0 * 8] = wv;
        // B(kt): wave w loads its 4 granule-groups (ct = w)
#pragma unroll
        for (int j2 = 0; j2 < 4; ++j2) {
            const bf16_t* src = pwL1 + ((size_t)kt * 1024 + wid * 256 + j2 * 64) * 8 + (size_t)lane * 8;
            glds16(src, &lB[(wid * 4 + j2) * 512]);
        }
        if (kt < 7) {
            const float4* p = (const float4*)(xT + (kt + 1) * 32);
            px0 = p[0]; px1 = p[1];
        }
        __syncthreads();   // staged data ready
        bf16x8 af[4];
#pragma unroll
        for (int i = 0; i < 4; ++i)
            af[i] = *(const bf16x8*)&lA[(i * 16 + lrow) * 40 + lq * 8];
#pragma unroll
        for (int j = 0; j < 4; ++j) {
            bf16x8 bfr = *(const bf16x8*)&lB[(wid * 4 + j) * 512 + lane * 8];
#pragma unroll
            for (int i = 0; i < 4; ++i)
                acc[i][j] = __builtin_amdgcn_mfma_f32_16x16x32_bf16(af[i], bfr, acc[i][j], 0, 0, 0);
        }
    }
    size_t obase = (size_t)t * HP * HD + (size_t)(1 + m0) * HD;
#pragma unroll
    for (int j = 0; j < 4; ++j) {
        int col = wid * 64 + j * 16 + lrow;
        float bj = b[col];
#pragma unroll
        for (int i = 0; i < 4; ++i)
#pragma unroll
            for (int r = 0; r < 4; ++r) {
                int orow = i * 16 + lq * 4 + r;
                h0[obase + (size_t)orow * HD + col] = (bf16_t)(acc[i][j][r] + bj);
            }
    }
}

// =========================================================
// layer: 4 ops in one 8-iter K loop; conv via row-shifted LDS reads.
// Single-buffer B (3 blocks/CU). DO_RED: fused column sum/max partials.
// =========================================================
template <int DO_RED>
__global__ __launch_bounds__(256, 3) void layer_kernel(
    const bf16_t* __restrict__ hin, bf16_t* __restrict__ hout,
    const bf16_t* __restrict__ pwS, const bf16_t* __restrict__ pwT,
    const float* __restrict__ lin_b, const float* __restrict__ rel_lin_b,
    const float* __restrict__ conv_b, const float* __restrict__ rel_conv_b,
    const float* __restrict__ tw5, float* __restrict__ ps, float* __restrict__ pm) {
    __shared__ __align__(16) bf16_t lA[130 * 40];
    __shared__ __align__(16) bf16_t lB[16384];
    __shared__ float lsum[4][64], lmax[4][64];
    const int tid = threadIdx.x, lane = tid & 63, wid = tid >> 6;
    const int bx = blockIdx.x;
    const int t = bx >> 8, rb = bx & 255, mt = rb >> 2, ct = rb & 3;
    const int m0 = mt * 128, c0 = ct * 64;
    const int wm = (wid >> 1) * 64, wn = (wid & 1) * 32;
    const int lrow = lane & 15, lq = lane >> 4;
    const int wj2 = wn >> 4;
    const bf16_t* aG = hin + (size_t)t * HP * HD + (size_t)m0 * HD;  // lds row R <-> hp row m0+R
    const bf16_t* pwTt = pwT + (size_t)t * 262144;
    const int r0 = tid >> 1, kq0 = (tid & 1) * 2;
    const int r1 = 128 + (tid >> 1);
    const bool tail = (tid < 4);

    f32x4 acc[4][4][2];
#pragma unroll
    for (int m = 0; m < 4; ++m)
#pragma unroll
        for (int i = 0; i < 4; ++i)
#pragma unroll
            for (int j = 0; j < 2; ++j) acc[m][i][j] = (f32x4){0.f, 0.f, 0.f, 0.f};

    bf16x8 pa0, pa1, pb0, pb1;
    pa0 = *(const bf16x8*)(aG + (size_t)r0 * HD + kq0 * 8);
    pa1 = *(const bf16x8*)(aG + (size_t)r0 * HD + kq0 * 8 + 8);
    if (tail) {
        pb0 = *(const bf16x8*)(aG + (size_t)r1 * HD + kq0 * 8);
        pb1 = *(const bf16x8*)(aG + (size_t)r1 * HD + kq0 * 8 + 8);
    }
    for (int kt = 0; kt < 8; ++kt) {
        __syncthreads();   // previous MFMA phase done with lA/lB
        *(bf16x8*)&lA[r0 * 40 + kq0 * 8] = pa0;
        *(bf16x8*)&lA[r0 * 40 + kq0 * 8 + 8] = pa1;
        if (tail) {
            *(bf16x8*)&lA[r1 * 40 + kq0 * 8] = pb0;
            *(bf16x8*)&lA[r1 * 40 + kq0 * 8 + 8] = pb1;
        }
        // B(kt): 32 glds, 8 per wave
#pragma unroll
        for (int q = 0; q < 8; ++q) {
            int tk = wid * 8 + q, half = tk >> 4, grp = tk & 15;
            const bf16_t* src = (half ? pwTt : pwS) + (size_t)((kt * 4 + ct) * 16 + grp) * 512 + (size_t)lane * 8;
            glds16(src, &lB[(half * 16 + grp) * 512]);
        }
        if (kt < 7) {
            pa0 = *(const bf16x8*)(aG + (size_t)r0 * HD + (kt + 1) * 32 + kq0 * 8);
            pa1 = *(const bf16x8*)(aG + (size_t)r0 * HD + (kt + 1) * 32 + kq0 * 8 + 8);
            if (tail) {
                pb0 = *(const bf16x8*)(aG + (size_t)r1 * HD + (kt + 1) * 32 + kq0 * 8);
                pb1 = *(const bf16x8*)(aG + (size_t)r1 * HD + (kt + 1) * 32 + kq0 * 8 + 8);
            }
        }
        __syncthreads();   // staged data ready
        bf16x8 af[4];
        load_af(af, lA, 1, wm, lrow, lq);            // center shift
        do_mat(af, lB, 0 + 0 + wj2, lane, acc[0]);   // lin
        do_mat(af, lB, 16 + 0 + wj2, lane, acc[1]);  // rel-lin
        do_mat(af, lB, 0 + 8 + wj2, lane, acc[2]);   // conv tap 1
        do_mat(af, lB, 16 + 8 + wj2, lane, acc[3]);  // rconv tap 1
        load_af(af, lA, 0, wm, lrow, lq);            // shift -1
        do_mat(af, lB, 0 + 4 + wj2, lane, acc[2]);   // conv tap 0
        do_mat(af, lB, 16 + 4 + wj2, lane, acc[3]);
        load_af(af, lA, 2, wm, lrow, lq);            // shift +1
        do_mat(af, lB, 0 + 12 + wj2, lane, acc[2]);  // conv tap 2
        do_mat(af, lB, 16 + 12 + wj2, lane, acc[3]);
    }
    const float w0 = tw5[0], w1 = tw5[1], w2 = tw5[2], w3 = tw5[3], w4 = tw5[4];
    const float* rb1 = rel_lin_b + t * 256;
    const float* rb3 = rel_conv_b + t * 256;
    size_t obase = (size_t)t * HP * HD + (size_t)(1 + m0) * HD;
    float csum[2], cmax[2];
#pragma unroll
    for (int j = 0; j < 2; ++j) { csum[j] = 0.f; cmax[j] = -3.4e38f; }
#pragma unroll
    for (int j = 0; j < 2; ++j) {
        int col = c0 + wn + j * 16 + lrow;
        float b0 = lin_b[col], b1 = rb1[col], b2 = conv_b[col], b3 = rb3[col];
#pragma unroll
        for (int i = 0; i < 4; ++i)
#pragma unroll
            for (int r = 0; r < 4; ++r) {
                int orow = wm + i * 16 + lq * 4 + r;
                size_t idx = obase + (size_t)orow * HD + col;
                float v = w0 * frelu(acc[0][i][j][r] + b0)
                        + w1 * frelu(acc[1][i][j][r] + b1)
                        + w2 * frelu(acc[2][i][j][r] + b2)
                        + w3 * frelu(acc[3][i][j][r] + b3)
                        + w4 * (float)hin[idx];
                hout[idx] = (bf16_t)v;
                if (DO_RED) { csum[j] += v; cmax[j] = fmaxf(cmax[j], v); }
            }
    }
    if (DO_RED) {
        // reduce over lq (rows within wave): lanes differ in bits 4,5
#pragma unroll
        for (int j = 0; j < 2; ++j) {
            csum[j] += __shfl_xor(csum[j], 16, 64);
            csum[j] += __shfl_xor(csum[j], 32, 64);
            float o1 = __shfl_xor(cmax[j], 16, 64); cmax[j] = fmaxf(cmax[j], o1);
            float o2 = __shfl_xor(cmax[j], 32, 64); cmax[j] = fmaxf(cmax[j], o2);
        }
        __syncthreads();   // lA/lB dead; reuse barrier for lsum
        if (lq == 0) {
#pragma unroll
            for (int j = 0; j < 2; ++j) {
                lsum[wid][wn + j * 16 + lrow] = csum[j];
                lmax[wid][wn + j * 16 + lrow] = cmax[j];
            }
        }
        __syncthreads();
        if (tid < 64) {
            int w0i = tid >> 5;
            float S = lsum[w0i][tid] + lsum[w0i + 2][tid];
            float M = fmaxf(lmax[w0i][tid], lmax[w0i + 2][tid]);
            int g = t * 64 + mt;   // FIX: 64 m-tiles per type (was t*32+mt -> collisions)
            ps[g * 256 + c0 + tid] = S;
            pm[g * 256 + c0 + tid] = M;
        }
    }
}

// =========================================================
// final: combine [256][256] partials, agg, head
// =========================================================
__global__ void reduce2_kernel(const float* __restrict__ ps, const float* __restrict__ pm,
                               const float* __restrict__ out_w, const float* __restrict__ out_b,
                               const float* __restrict__ tws, float* __restrict__ out) {
    __shared__ float aggL[256];
    int c = threadIdx.x;
    float s = 0.f, m = -3.4e38f;
#pragma unroll 8
    for (int g = 0; g < 256; ++g) {
        s += ps[g * 256 + c];
        m = fmaxf(m, pm[g * 256 + c]);
    }
    float aw0 = tws[10], aw1 = tws[11], aw2 = tws[12];
    aggL[c] = aw0 * s + aw1 * (s * (1.0f / 32768.f)) + aw2 * m;
    __syncthreads();
    if (c < DOUT) {
        float o = out_b[c];
        for (int e = 0; e < 256; ++e) o += aggL[e] * out_w[e * DOUT + c];
        out[c] = o;
    }
}

extern "C" void kernel_launch(void* const* d_in, const int* in_sizes, int n_in,
                              void* d_out, int out_size, void* d_ws, size_t ws_size,
                              hipStream_t stream) {
    const float* x          = (const float*)d_in[0];
    const float* lin1_w     = (const float*)d_in[1];
    const float* lin1_b     = (const float*)d_in[2];
    const float* lin_w      = (const float*)d_in[3];
    const float* lin_b      = (const float*)d_in[4];
    const float* rel_lin_w  = (const float*)d_in[5];
    const float* rel_lin_b  = (const float*)d_in[6];
    const float* conv_w     = (const float*)d_in[7];
    const float* conv_b     = (const float*)d_in[8];
    const float* rel_conv_w = (const float*)d_in[9];
    const float* rel_conv_b = (const float*)d_in[10];
    const float* out_w      = (const float*)d_in[11];
    const float* out_b      = (const float*)d_in[12];
    const float* trans_arch = (const float*)d_in[13];
    const float* agg_arch   = (const float*)d_in[14];

    char* ws = (char*)d_ws;
    bf16_t* h0 = (bf16_t*)(ws + H0_OFF);
    bf16_t* h1 = (bf16_t*)(ws + H1_OFF);
    bf16_t* pw = (bf16_t*)(ws + PW_OFF);
    float* tws = (float*)(ws + TW_OFF);
    float* ps  = (float*)(ws + PS_OFF);
    float* pm  = (float*)(ws + PM_OFF);
    float* outp = (float*)d_out;

    pack_kernel<<<410, 256, 0, stream>>>(lin1_w, lin_w, rel_lin_w, conv_w, rel_conv_w,
                                         trans_arch, agg_arch, pw, tws, h0, h1);
    lin1_kernel<<<512, 256, 0, stream>>>(x, h0, pw + (size_t)PWG_L1 * 8, lin1_b);
    layer_kernel<0><<<1024, 256, 0, stream>>>(h0, h1,
        pw + (size_t)PWG_SH(0) * 8, pw + (size_t)PWG_TY(0) * 8,
        lin_b, rel_lin_b, conv_b, rel_conv_b, tws, nullptr, nullptr);
    layer_kernel<1><<<1024, 256, 0, stream>>>(h1, h0,
        pw + (size_t)PWG_SH(1) * 8, pw + (size_t)PWG_TY(1) * 8,
        lin_b + 256, rel_lin_b + 1024, conv_b + 256, rel_conv_b + 1024, tws + 5, ps, pm);
    reduce2_kernel<<<1, 256, 0, stream>>>(ps, pm, out_w, out_b, tws, outp);
}

// Round 6
// 198.409 us; speedup vs baseline: 1.6702x; 1.6702x over previous
//
#include <hip/hip_runtime.h>
#include <hip/hip_bf16.h>
#include <math.h>

#define NN 8192
#define HP 8194   // per-type rows incl 1 zero guard row each end
#define HD 256
#define DOUT 64

typedef __bf16 bf16_t;
typedef __bf16 bf16x8 __attribute__((ext_vector_type(8)));
typedef float f32x4 __attribute__((ext_vector_type(4)));

// ---------------- workspace layout (bytes) ----------------
#define H0_OFF 0ull
#define H1_OFF 16781312ull
#define PW_OFF 33562624ull          // 335872 granules * 16B = 5,373,952
#define TW_OFF 38936576ull
#define PS_OFF 38936832ull          // [256][256] f32 = 256KB
#define PM_OFF 39198976ull          // [256][256] f32 = 256KB (end 39461120)
// stage-1 reduce partials live in the dead h1 region
#define PS2_OFF H1_OFF              // [64][256] f32 = 64KB
#define PM2_OFF (H1_OFF + 65536ull) // [64][256] f32 = 64KB
// pw granule indices
#define PWG_L1 0
#define PWG_SH(l) (8192 + (l)*32768)
#define PWG_TY(l) (73728 + (l)*131072)

__device__ __forceinline__ void glds16(const void* g, void* l) {
    __builtin_amdgcn_global_load_lds(
        (const __attribute__((address_space(1))) void*)g,
        (__attribute__((address_space(3))) void*)l, 16, 0, 0);
}

__device__ __forceinline__ float frelu(float v) { return v > 0.f ? v : 0.f; }

// =========================================================
// pack: fully-coalesced reads via per-block LDS transpose.
// =========================================================
__global__ __launch_bounds__(256) void pack_kernel(
    const float* __restrict__ lin1_w, const float* __restrict__ lin_w,
    const float* __restrict__ rel_lin_w, const float* __restrict__ conv_w,
    const float* __restrict__ rel_conv_w, const float* __restrict__ trans_arch,
    const float* __restrict__ agg_arch, bf16_t* __restrict__ pw,
    float* __restrict__ tws, bf16_t* __restrict__ h0, bf16_t* __restrict__ h1) {
    __shared__ float lt[32 * 257];    // 32.9KB (lin path); conv path uses 64*100
    const int tid = threadIdx.x, bx = blockIdx.x;
    if (bx < 88) {
        // lin-family: block = (matrix m, kt). 32 k-rows x 256 n staged.
        int m = bx >> 3, kt = bx & 7;
        const float* src; size_t img; bool l1 = (m == 0);
        if (m == 0) { src = lin1_w; img = 0; }
        else if (m <= 2) { int l = m - 1; src = lin_w + (size_t)l * 65536; img = PWG_SH(l); }
        else { int u = m - 3; int l = u >> 2, tt = u & 3;
            src = rel_lin_w + (size_t)(l * 4 + tt) * 65536;
            img = PWG_TY(l) + (size_t)tt * 32768; }
        const float4* s4 = (const float4*)(src + (size_t)kt * 32 * 256);
#pragma unroll
        for (int i = 0; i < 8; ++i) {
            int idx = tid + 256 * i;
            float4 v = s4[idx];
            int k = idx >> 6, n = (idx * 4) & 255;
            float* p = &lt[k * 257 + n];
            p[0] = v.x; p[1] = v.y; p[2] = v.z; p[3] = v.w;
        }
        __syncthreads();
        int j2 = tid >> 6, lq = (tid >> 4) & 3, lrow = tid & 15;
#pragma unroll
        for (int ct = 0; ct < 4; ++ct) {
            int n = ct * 64 + j2 * 16 + lrow;
            bf16x8 wv;
#pragma unroll
            for (int e = 0; e < 8; ++e) wv[e] = (bf16_t)lt[(lq * 8 + e) * 257 + n];
            size_t g = l1 ? (img + (size_t)kt * 1024 + ct * 256 + tid)
                          : (img + (size_t)kt * 4096 + ct * 1024 + tid);
            *(bf16x8*)(pw + g * 8) = wv;
        }
    } else if (bx < 408) {
        // conv-family: block = (inst, kt, ct). 64 n-rows x 96 floats staged.
        int idx = bx - 88;
        int inst = idx >> 5, r = idx & 31, kt = r >> 2, ct = r & 3;
        const float* src; size_t img;
        if (inst < 2) { src = conv_w + (size_t)inst * 196608; img = PWG_SH(inst); }
        else { int u = inst - 2; int l = u >> 2, tt = u & 3;
            src = rel_conv_w + (size_t)(l * 4 + tt) * 196608;
            img = PWG_TY(l) + (size_t)tt * 32768; }
        {
            int rl = tid >> 2, q0 = tid & 3;
            int n = ct * 64 + rl;
            const float4* rb = (const float4*)(src) + (size_t)n * 192 + kt * 24;
#pragma unroll
            for (int i = 0; i < 6; ++i) {
                float4 v = rb[q0 + 4 * i];
                float* p = &lt[rl * 100 + (q0 + 4 * i) * 4];
                p[0] = v.x; p[1] = v.y; p[2] = v.z; p[3] = v.w;
            }
        }
        __syncthreads();
        int j2 = tid >> 6, lq = (tid >> 4) & 3, lrow = tid & 15;
        int nl = j2 * 16 + lrow;
#pragma unroll
        for (int s = 1; s <= 3; ++s) {
            bf16x8 wv;
#pragma unroll
            for (int e = 0; e < 8; ++e) wv[e] = (bf16_t)lt[nl * 100 + (lq * 8 + e) * 3 + (s - 1)];
            size_t g = img + (size_t)kt * 4096 + ct * 1024 + s * 256 + tid;
            *(bf16x8*)(pw + g * 8) = wv;
        }
    } else if (bx == 408) {
        // zero guard rows of both h buffers
        for (int i = tid; i < 4096; i += 256) {
            int row_id = i >> 8, col = i & 255;
            int buf = row_id >> 3, t_ = (row_id >> 1) & 3, side = row_id & 1;
            bf16_t* hb = buf ? h1 : h0;
            hb[((size_t)t_ * HP + (side ? (HP - 1) : 0)) * HD + col] = (bf16_t)0.f;
        }
    } else {
        if (tid == 0) {
            for (int l = 0; l < 2; ++l) {
                float m = trans_arch[l * 5];
                for (int i = 1; i < 5; ++i) m = fmaxf(m, trans_arch[l * 5 + i]);
                float e[5], s = 0.f;
                for (int i = 0; i < 5; ++i) { e[i] = __expf(trans_arch[l * 5 + i] - m); s += e[i]; }
                for (int i = 0; i < 5; ++i) tws[l * 5 + i] = e[i] / s;
            }
            float m = fmaxf(fmaxf(agg_arch[0], agg_arch[1]), agg_arch[2]);
            float e0 = __expf(agg_arch[0] - m), e1 = __expf(agg_arch[1] - m), e2 = __expf(agg_arch[2] - m);
            float s = e0 + e1 + e2;
            tws[10] = e0 / s; tws[11] = e1 / s; tws[12] = e2 / s;
        }
    }
}

__device__ __forceinline__ void load_af(bf16x8 af[4], const bf16_t* lA,
                                        int sh, int wm, int lrow, int lq) {
#pragma unroll
    for (int i = 0; i < 4; ++i)
        af[i] = *(const bf16x8*)&lA[(sh + wm + i * 16 + lrow) * 40 + lq * 8];
}

__device__ __forceinline__ void do_mat(const bf16x8 af[4], const bf16_t* Bb,
                                       int grpbase, int lane, f32x4 acc[4][2]) {
#pragma unroll
    for (int j = 0; j < 2; ++j) {
        bf16x8 bfr = *(const bf16x8*)&Bb[(grpbase + j) * 512 + lane * 8];
#pragma unroll
        for (int i = 0; i < 4; ++i)
            acc[i][j] = __builtin_amdgcn_mfma_f32_16x16x32_bf16(af[i], bfr, acc[i][j], 0, 0, 0);
    }
}

// =========================================================
// lin1 (fused fp32->bf16): h0 = x @ lin1_w + b. 64x256 tile, x read once.
// =========================================================
__global__ __launch_bounds__(256, 2) void lin1_kernel(
    const float* __restrict__ x, bf16_t* __restrict__ h0,
    const bf16_t* __restrict__ pwL1, const float* __restrict__ b) {
    __shared__ __align__(16) bf16_t lA[64 * 40];
    __shared__ __align__(16) bf16_t lB[8192];
    const int tid = threadIdx.x, lane = tid & 63, wid = tid >> 6;
    const int bx = blockIdx.x;
    const int t = bx >> 7, mt = bx & 127;
    const int m0 = mt * 64;
    const int lrow = lane & 15, lq = lane >> 4;
    const int r0 = tid >> 2, kq0 = tid & 3;
    const float* xT = x + (size_t)t * NN * HD + (size_t)(m0 + r0) * HD + kq0 * 8;

    f32x4 acc[4][4];
#pragma unroll
    for (int i = 0; i < 4; ++i)
#pragma unroll
        for (int j = 0; j < 4; ++j) acc[i][j] = (f32x4){0.f, 0.f, 0.f, 0.f};

    float4 px0, px1;
    { const float4* p = (const float4*)xT; px0 = p[0]; px1 = p[1]; }

    for (int kt = 0; kt < 8; ++kt) {
        __syncthreads();   // previous MFMA phase done with lA/lB
        bf16x8 wv;
        wv[0]=(bf16_t)px0.x; wv[1]=(bf16_t)px0.y; wv[2]=(bf16_t)px0.z; wv[3]=(bf16_t)px0.w;
        wv[4]=(bf16_t)px1.x; wv[5]=(bf16_t)px1.y; wv[6]=(bf16_t)px1.z; wv[7]=(bf16_t)px1.w;
        *(bf16x8*)&lA[r0 * 40 + kq0 * 8] = wv;
        // B(kt): wave w loads its 4 granule-groups (ct = w)
#pragma unroll
        for (int j2 = 0; j2 < 4; ++j2) {
            const bf16_t* src = pwL1 + ((size_t)kt * 1024 + wid * 256 + j2 * 64) * 8 + (size_t)lane * 8;
            glds16(src, &lB[(wid * 4 + j2) * 512]);
        }
        if (kt < 7) {
            const float4* p = (const float4*)(xT + (kt + 1) * 32);
            px0 = p[0]; px1 = p[1];
        }
        __syncthreads();   // staged data ready
        bf16x8 af[4];
#pragma unroll
        for (int i = 0; i < 4; ++i)
            af[i] = *(const bf16x8*)&lA[(i * 16 + lrow) * 40 + lq * 8];
#pragma unroll
        for (int j = 0; j < 4; ++j) {
            bf16x8 bfr = *(const bf16x8*)&lB[(wid * 4 + j) * 512 + lane * 8];
#pragma unroll
            for (int i = 0; i < 4; ++i)
                acc[i][j] = __builtin_amdgcn_mfma_f32_16x16x32_bf16(af[i], bfr, acc[i][j], 0, 0, 0);
        }
    }
    size_t obase = (size_t)t * HP * HD + (size_t)(1 + m0) * HD;
#pragma unroll
    for (int j = 0; j < 4; ++j) {
        int col = wid * 64 + j * 16 + lrow;
        float bj = b[col];
#pragma unroll
        for (int i = 0; i < 4; ++i)
#pragma unroll
            for (int r = 0; r < 4; ++r) {
                int orow = i * 16 + lq * 4 + r;
                h0[obase + (size_t)orow * HD + col] = (bf16_t)(acc[i][j][r] + bj);
            }
    }
}

// =========================================================
// layer: 4 ops in one 8-iter K loop; conv via row-shifted LDS reads.
// (256,2): 128 AGPR acc + ~128 VGPR fits without spill (R3 measured;
// (256,3) spilled: VGPR 84, WRITE_SIZE 100MB, 2.4x slower — R5).
// XCD swizzle: 4 ct-blocks of one (t,mt) share an XCD -> A-slab L2 reuse.
// DO_RED: fused column sum/max partials.
// =========================================================
template <int DO_RED>
__global__ __launch_bounds__(256, 2) void layer_kernel(
    const bf16_t* __restrict__ hin, bf16_t* __restrict__ hout,
    const bf16_t* __restrict__ pwS, const bf16_t* __restrict__ pwT,
    const float* __restrict__ lin_b, const float* __restrict__ rel_lin_b,
    const float* __restrict__ conv_b, const float* __restrict__ rel_conv_b,
    const float* __restrict__ tw5, float* __restrict__ ps, float* __restrict__ pm) {
    __shared__ __align__(16) bf16_t lA[130 * 40];
    __shared__ __align__(16) bf16_t lB[16384];
    __shared__ float lsum[4][64], lmax[4][64];
    const int tid = threadIdx.x, lane = tid & 63, wid = tid >> 6;
    const int bx = blockIdx.x;
    // XCD-aware swizzle: xcd = bx&7 (HW round-robin); all 4 ct variants of a
    // (t,mt) pair map to the same xcd so the A-slab is fetched once per XCD.
    const int xcd = bx & 7, q = bx >> 3;
    const int ct = q & 3, tm = (q >> 2) * 8 + xcd;
    const int t = tm >> 6, mt = tm & 63;
    const int m0 = mt * 128, c0 = ct * 64;
    const int wm = (wid >> 1) * 64, wn = (wid & 1) * 32;
    const int lrow = lane & 15, lq = lane >> 4;
    const int wj2 = wn >> 4;
    const bf16_t* aG = hin + (size_t)t * HP * HD + (size_t)m0 * HD;  // lds row R <-> hp row m0+R
    const bf16_t* pwTt = pwT + (size_t)t * 262144;
    const int r0 = tid >> 1, kq0 = (tid & 1) * 2;
    const int r1 = 128 + (tid >> 1);
    const bool tail = (tid < 4);

    f32x4 acc[4][4][2];
#pragma unroll
    for (int m = 0; m < 4; ++m)
#pragma unroll
        for (int i = 0; i < 4; ++i)
#pragma unroll
            for (int j = 0; j < 2; ++j) acc[m][i][j] = (f32x4){0.f, 0.f, 0.f, 0.f};

    bf16x8 pa0, pa1, pb0, pb1;
    pa0 = *(const bf16x8*)(aG + (size_t)r0 * HD + kq0 * 8);
    pa1 = *(const bf16x8*)(aG + (size_t)r0 * HD + kq0 * 8 + 8);
    if (tail) {
        pb0 = *(const bf16x8*)(aG + (size_t)r1 * HD + kq0 * 8);
        pb1 = *(const bf16x8*)(aG + (size_t)r1 * HD + kq0 * 8 + 8);
    }
    for (int kt = 0; kt < 8; ++kt) {
        __syncthreads();   // previous MFMA phase done with lA/lB
        *(bf16x8*)&lA[r0 * 40 + kq0 * 8] = pa0;
        *(bf16x8*)&lA[r0 * 40 + kq0 * 8 + 8] = pa1;
        if (tail) {
            *(bf16x8*)&lA[r1 * 40 + kq0 * 8] = pb0;
            *(bf16x8*)&lA[r1 * 40 + kq0 * 8 + 8] = pb1;
        }
        // B(kt): 32 glds, 8 per wave
#pragma unroll
        for (int qq = 0; qq < 8; ++qq) {
            int tk = wid * 8 + qq, half = tk >> 4, grp = tk & 15;
            const bf16_t* src = (half ? pwTt : pwS) + (size_t)((kt * 4 + ct) * 16 + grp) * 512 + (size_t)lane * 8;
            glds16(src, &lB[(half * 16 + grp) * 512]);
        }
        if (kt < 7) {
            pa0 = *(const bf16x8*)(aG + (size_t)r0 * HD + (kt + 1) * 32 + kq0 * 8);
            pa1 = *(const bf16x8*)(aG + (size_t)r0 * HD + (kt + 1) * 32 + kq0 * 8 + 8);
            if (tail) {
                pb0 = *(const bf16x8*)(aG + (size_t)r1 * HD + (kt + 1) * 32 + kq0 * 8);
                pb1 = *(const bf16x8*)(aG + (size_t)r1 * HD + (kt + 1) * 32 + kq0 * 8 + 8);
            }
        }
        __syncthreads();   // staged data ready
        bf16x8 af[4];
        load_af(af, lA, 1, wm, lrow, lq);            // center shift
        do_mat(af, lB, 0 + 0 + wj2, lane, acc[0]);   // lin
        do_mat(af, lB, 16 + 0 + wj2, lane, acc[1]);  // rel-lin
        do_mat(af, lB, 0 + 8 + wj2, lane, acc[2]);   // conv tap 1
        do_mat(af, lB, 16 + 8 + wj2, lane, acc[3]);  // rconv tap 1
        load_af(af, lA, 0, wm, lrow, lq);            // shift -1
        do_mat(af, lB, 0 + 4 + wj2, lane, acc[2]);   // conv tap 0
        do_mat(af, lB, 16 + 4 + wj2, lane, acc[3]);
        load_af(af, lA, 2, wm, lrow, lq);            // shift +1
        do_mat(af, lB, 0 + 12 + wj2, lane, acc[2]);  // conv tap 2
        do_mat(af, lB, 16 + 12 + wj2, lane, acc[3]);
    }
    const float w0 = tw5[0], w1 = tw5[1], w2 = tw5[2], w3 = tw5[3], w4 = tw5[4];
    const float* rb1 = rel_lin_b + t * 256;
    const float* rb3 = rel_conv_b + t * 256;
    size_t obase = (size_t)t * HP * HD + (size_t)(1 + m0) * HD;
    float csum[2], cmax[2];
#pragma unroll
    for (int j = 0; j < 2; ++j) { csum[j] = 0.f; cmax[j] = -3.4e38f; }
#pragma unroll
    for (int j = 0; j < 2; ++j) {
        int col = c0 + wn + j * 16 + lrow;
        float b0 = lin_b[col], b1 = rb1[col], b2 = conv_b[col], b3 = rb3[col];
#pragma unroll
        for (int i = 0; i < 4; ++i)
#pragma unroll
            for (int r = 0; r < 4; ++r) {
                int orow = wm + i * 16 + lq * 4 + r;
                size_t idx = obase + (size_t)orow * HD + col;
                float v = w0 * frelu(acc[0][i][j][r] + b0)
                        + w1 * frelu(acc[1][i][j][r] + b1)
                        + w2 * frelu(acc[2][i][j][r] + b2)
                        + w3 * frelu(acc[3][i][j][r] + b3)
                        + w4 * (float)hin[idx];
                hout[idx] = (bf16_t)v;
                if (DO_RED) { csum[j] += v; cmax[j] = fmaxf(cmax[j], v); }
            }
    }
    if (DO_RED) {
        // reduce over lq (rows within wave): lanes differ in bits 4,5
#pragma unroll
        for (int j = 0; j < 2; ++j) {
            csum[j] += __shfl_xor(csum[j], 16, 64);
            csum[j] += __shfl_xor(csum[j], 32, 64);
            float o1 = __shfl_xor(cmax[j], 16, 64); cmax[j] = fmaxf(cmax[j], o1);
            float o2 = __shfl_xor(cmax[j], 32, 64); cmax[j] = fmaxf(cmax[j], o2);
        }
        __syncthreads();   // lA/lB dead; reuse barrier for lsum
        if (lq == 0) {
#pragma unroll
            for (int j = 0; j < 2; ++j) {
                lsum[wid][wn + j * 16 + lrow] = csum[j];
                lmax[wid][wn + j * 16 + lrow] = cmax[j];
            }
        }
        __syncthreads();
        if (tid < 64) {
            int w0i = tid >> 5;
            float S = lsum[w0i][tid] + lsum[w0i + 2][tid];
            float M = fmaxf(lmax[w0i][tid], lmax[w0i + 2][tid]);
            int g = t * 64 + mt;   // 64 m-tiles per type
            ps[g * 256 + c0 + tid] = S;
            pm[g * 256 + c0 + tid] = M;
        }
    }
}

// =========================================================
// final reduce, two stages: 64-block partial combine, then head
// =========================================================
__global__ __launch_bounds__(256) void reduce2a_kernel(
    const float* __restrict__ ps, const float* __restrict__ pm,
    float* __restrict__ ps2, float* __restrict__ pm2) {
    int c = threadIdx.x, b = blockIdx.x;
    float s = 0.f, m = -3.4e38f;
#pragma unroll
    for (int i = 0; i < 4; ++i) {
        int g = b * 4 + i;
        s += ps[g * 256 + c];
        m = fmaxf(m, pm[g * 256 + c]);
    }
    ps2[b * 256 + c] = s;
    pm2[b * 256 + c] = m;
}

__global__ __launch_bounds__(256) void reduce2b_kernel(
    const float* __restrict__ ps2, const float* __restrict__ pm2,
    const float* __restrict__ out_w, const float* __restrict__ out_b,
    const float* __restrict__ tws, float* __restrict__ out) {
    __shared__ float aggL[256];
    int c = threadIdx.x;
    float s = 0.f, m = -3.4e38f;
#pragma unroll 4
    for (int g = 0; g < 64; ++g) {
        s += ps2[g * 256 + c];
        m = fmaxf(m, pm2[g * 256 + c]);
    }
    float aw0 = tws[10], aw1 = tws[11], aw2 = tws[12];
    aggL[c] = aw0 * s + aw1 * (s * (1.0f / 32768.f)) + aw2 * m;
    __syncthreads();
    if (c < DOUT) {
        float o = out_b[c];
        for (int e = 0; e < 256; ++e) o += aggL[e] * out_w[e * DOUT + c];
        out[c] = o;
    }
}

extern "C" void kernel_launch(void* const* d_in, const int* in_sizes, int n_in,
                              void* d_out, int out_size, void* d_ws, size_t ws_size,
                              hipStream_t stream) {
    const float* x          = (const float*)d_in[0];
    const float* lin1_w     = (const float*)d_in[1];
    const float* lin1_b     = (const float*)d_in[2];
    const float* lin_w      = (const float*)d_in[3];
    const float* lin_b      = (const float*)d_in[4];
    const float* rel_lin_w  = (const float*)d_in[5];
    const float* rel_lin_b  = (const float*)d_in[6];
    const float* conv_w     = (const float*)d_in[7];
    const float* conv_b     = (const float*)d_in[8];
    const float* rel_conv_w = (const float*)d_in[9];
    const float* rel_conv_b = (const float*)d_in[10];
    const float* out_w      = (const float*)d_in[11];
    const float* out_b      = (const float*)d_in[12];
    const float* trans_arch = (const float*)d_in[13];
    const float* agg_arch   = (const float*)d_in[14];

    char* ws = (char*)d_ws;
    bf16_t* h0 = (bf16_t*)(ws + H0_OFF);
    bf16_t* h1 = (bf16_t*)(ws + H1_OFF);
    bf16_t* pw = (bf16_t*)(ws + PW_OFF);
    float* tws = (float*)(ws + TW_OFF);
    float* ps  = (float*)(ws + PS_OFF);
    float* pm  = (float*)(ws + PM_OFF);
    float* ps2 = (float*)(ws + PS2_OFF);   // h1 region, dead after layer1
    float* pm2 = (float*)(ws + PM2_OFF);
    float* outp = (float*)d_out;

    pack_kernel<<<410, 256, 0, stream>>>(lin1_w, lin_w, rel_lin_w, conv_w, rel_conv_w,
                                         trans_arch, agg_arch, pw, tws, h0, h1);
    lin1_kernel<<<512, 256, 0, stream>>>(x, h0, pw + (size_t)PWG_L1 * 8, lin1_b);
    layer_kernel<0><<<1024, 256, 0, stream>>>(h0, h1,
        pw + (size_t)PWG_SH(0) * 8, pw + (size_t)PWG_TY(0) * 8,
        lin_b, rel_lin_b, conv_b, rel_conv_b, tws, nullptr, nullptr);
    layer_kernel<1><<<1024, 256, 0, stream>>>(h1, h0,
        pw + (size_t)PWG_SH(1) * 8, pw + (size_t)PWG_TY(1) * 8,
        lin_b + 256, rel_lin_b + 1024, conv_b + 256, rel_conv_b + 1024, tws + 5, ps, pm);
    reduce2a_kernel<<<64, 256, 0, stream>>>(ps, pm, ps2, pm2);
    reduce2b_kernel<<<1, 256, 0, stream>>>(ps2, pm2, out_w, out_b, tws, outp);
}